// Round 8
// baseline (207.126 us; speedup 1.0000x reference)
//
#include <hip/hip_runtime.h>
#include <cstddef>

// Problem constants (B=4, S=2048, D=256, H=8, dh=32, d_ff=512), fp32 in/out.
constexpr int kB   = 4;
constexpr int kS   = 2048;
constexpr int kD   = 256;
constexpr int kH   = 8;
constexpr int kDH  = 32;
constexpr int kDFF = 512;
constexpr int kM   = kB * kS;   // 8192 token rows
constexpr int kMT  = kM / 128;  // 64 m-tiles of 128 rows
constexpr float kEps = 1e-5f;
// 1/sqrt(32) * log2(e): scores pre-scaled so softmax uses exp2 directly.
constexpr float kScaleL2E = 0.17677669529663687f * 1.4426950408889634f;

typedef float f32x4  __attribute__((ext_vector_type(4)));
typedef short bf16x8 __attribute__((ext_vector_type(8)));
typedef unsigned short u16;
typedef unsigned int   u32;

__device__ inline u16 f2bf(float x) {
    union { float f; unsigned u; } c; c.f = x;
    const unsigned r = c.u + 0x7fffu + ((c.u >> 16) & 1u);
    return (u16)(r >> 16);
}

// pack two fp32 -> two bf16 (truncation) in ONE v_perm_b32.
__device__ inline u32 pk_trunc(float lo, float hi) {
    union { float f; u32 u; } a, b; a.f = lo; b.f = hi;
    return __builtin_amdgcn_perm(b.u, a.u, 0x07060302u);
}

// Packed fragment-major layout (the attn-V trick, applied everywhere):
//   P[row/16][col/32][row&15][col&31], 512 u16 per 16x32 tile.
// A wave-fragment load (lane quad,l16 -> 8 u16 at (row&15)=l16, col quad*8..)
// is then ONE contiguous 1KB load: offset l16*32 + quad*8 within the tile.
__device__ inline size_t pkoff(int row, int col, int nkb) {
    return ((size_t)(row >> 4) * nkb + (col >> 5)) * 512
         + (row & 15) * 32 + (col & 31);
}

// ---------------------------------------------------------------------------
// prep_kernel = LayerNorm (blocks [0, kM/4)) + one-shot weight convert+pack
// (blocks [kM/4, kM/4+512), only on the LN1 dispatch). LN: 4 rows/block, one
// wave per row, pure-shuffle reduction, bf16 out PACKED fragment-major.
// Conv: {w_qkv,w_proj,w1,w2} fp32 -> bf16 fragment-major, same f2bf rounding.
// Region bases (u16): wq 0, wp 196608, w1 262144, w2 393216.
// ---------------------------------------------------------------------------
__global__ __launch_bounds__(256)
void prep_kernel(const float* __restrict__ x, const float* __restrict__ g,
                 const float* __restrict__ b, u16* __restrict__ y,
                 const float* __restrict__ wq, const float* __restrict__ wp,
                 const float* __restrict__ w1, const float* __restrict__ w2,
                 u16* __restrict__ wdst)
{
    if (blockIdx.x >= kM / 4) {
        // ---- weight convert+pack section (512 blocks) ----
        const int e0 = ((blockIdx.x - kM / 4) * 256 + threadIdx.x) * 4;
        const float* src; int off, K, base;
        if (e0 < 196608)      { src = wq; off = e0;          K = 256; base = 0; }
        else if (e0 < 262144) { src = wp; off = e0 - 196608; K = 256; base = 196608; }
        else if (e0 < 393216) { src = w1; off = e0 - 262144; K = 256; base = 262144; }
        else                  { src = w2; off = e0 - 393216; K = 512; base = 393216; }
        const float4 v = *(const float4*)&src[off];
        const int n = off / K, k = off - n * K;
        const size_t po = pkoff(n, k, K >> 5);    // k%4==0 -> ushort4 in-tile
        *(ushort4*)&wdst[base + po] =
            make_ushort4(f2bf(v.x), f2bf(v.y), f2bf(v.z), f2bf(v.w));
        return;
    }
    const int wave = threadIdx.x >> 6;
    const int lane = threadIdx.x & 63;
    const int row  = blockIdx.x * 4 + wave;
    const float4 v = *(const float4*)&x[(size_t)row * kD + lane * 4];
    float s1 = (v.x + v.y) + (v.z + v.w);
    float s2 = (v.x * v.x + v.y * v.y) + (v.z * v.z + v.w * v.w);
    #pragma unroll
    for (int off = 1; off < 64; off <<= 1) {
        s1 += __shfl_xor(s1, off);
        s2 += __shfl_xor(s2, off);
    }
    const float mu  = s1 * (1.0f / kD);
    const float var = s2 * (1.0f / kD) - mu * mu;
    const float inv = rsqrtf(var + kEps);
    const float4 g4 = *(const float4*)&g[lane * 4];
    const float4 b4 = *(const float4*)&b[lane * 4];
    *(ushort4*)&y[pkoff(row, lane * 4, kD >> 5)] = make_ushort4(
        f2bf((v.x - mu) * inv * g4.x + b4.x),
        f2bf((v.y - mu) * inv * g4.y + b4.y),
        f2bf((v.z - mu) * inv * g4.z + b4.z),
        f2bf((v.w - mu) * inv * g4.w + b4.w));
}

// ---------------------------------------------------------------------------
// bf16 MFMA NT GEMM v8: persistent m-loop + register-resident W.
// R7 post-mortem: three different memory structures (LDS-staged / gather /
// packed-coalesced) all land ~160us -> the inner-loop pattern is not the
// constraint; per-block fixed cost + un-amortized W walks are. v8:
//   * W fragments hoisted ONCE per block into registers (NI<=2 -> 64 VGPR,
//     NK<=16), amortized over MT m-tiles; k-loop = pure coalesced packed
//     A-loads + MFMAs. No LDS, no barrier.
//   * block processes MT m-tiles: m0 = (blockIdx.x + t*gridDim.x)*128 ->
//     half the blocks, prologue/epilogue amortized, cross-tile load overlap.
// Block tile 128(M) x NI*16(N), 4 waves; wave w owns rows [m0+16w,+16) and
// [m0+64+16w,+16); each W-fragment feeds two MFMAs. Bit-identical math.
// OUTMODE: 0 = fp32 (+RES), 1 = SiLU->bf16 PACKED (NKB=16 for ffn2),
// 2 = QKV split (Q pre-scaled, K natural, V quad-interleaved).
// ---------------------------------------------------------------------------
template<int NI, int OUTMODE, bool RES, int KTOT, int MT>
__global__ __launch_bounds__(256)
void gemm_ps(const u16* __restrict__ Ap, const u16* __restrict__ Wp,
             const float* __restrict__ bias, const float* __restrict__ res,
             float* __restrict__ Cf, u16* __restrict__ Cb,
             u16* __restrict__ KbP, u16* __restrict__ VtP, int N)
{
    constexpr int NK = KTOT / 32;
    constexpr int GX = kMT / MT;            // gridDim.x
    const int tid  = threadIdx.x;
    const int wave = tid >> 6;
    const int lane = tid & 63;
    const int quad = lane >> 4;
    const int l16  = lane & 15;
    const int n0 = blockIdx.y * (NI * 16);
    const int fo = l16 * 32 + quad * 8;     // in-tile fragment offset

    // ---- hoist W fragments once per block (wave-uniform addresses) ----
    bf16x8 wfr[NI][NK];
    #pragma unroll
    for (int ni = 0; ni < NI; ++ni)
        #pragma unroll
        for (int k = 0; k < NK; ++k)
            wfr[ni][k] = *(const bf16x8*)
                &Wp[(size_t)((n0 >> 4) + ni) * NK * 512 + (size_t)k * 512 + fo];

    float biasv[NI];
    #pragma unroll
    for (int ni = 0; ni < NI; ++ni) biasv[ni] = bias[n0 + ni * 16 + l16];

    #pragma unroll 1
    for (int t = 0; t < MT; ++t) {
        const int m0 = (blockIdx.x + t * GX) * 128;

        f32x4 acc[2][NI];
        #pragma unroll
        for (int mt = 0; mt < 2; ++mt)
            #pragma unroll
            for (int ni = 0; ni < NI; ++ni) acc[mt][ni] = {0.f, 0.f, 0.f, 0.f};

        const u16* a0p = Ap + (size_t)((m0 >> 4) + wave)     * NK * 512 + fo;
        const u16* a1p = Ap + (size_t)((m0 >> 4) + 4 + wave) * NK * 512 + fo;

        #pragma unroll 4
        for (int k = 0; k < NK; ++k) {
            const bf16x8 a0 = *(const bf16x8*)&a0p[(size_t)k * 512];
            const bf16x8 a1 = *(const bf16x8*)&a1p[(size_t)k * 512];
            #pragma unroll
            for (int ni = 0; ni < NI; ++ni) {
                acc[0][ni] = __builtin_amdgcn_mfma_f32_16x16x32_bf16(a0, wfr[ni][k], acc[0][ni], 0, 0, 0);
                acc[1][ni] = __builtin_amdgcn_mfma_f32_16x16x32_bf16(a1, wfr[ni][k], acc[1][ni], 0, 0, 0);
            }
        }

        // ---- epilogue (both m-halves) ----
        #pragma unroll
        for (int mt = 0; mt < 2; ++mt) {
            #pragma unroll
            for (int ni = 0; ni < NI; ++ni) {
                #pragma unroll
                for (int r = 0; r < 4; ++r) {
                    const int m = m0 + mt * 64 + wave * 16 + quad * 4 + r;
                    const int n = n0 + ni * 16 + l16;
                    float v = acc[mt][ni][r] + biasv[ni];
                    if (OUTMODE == 0) {
                        if (RES) v += res[(size_t)m * N + n];
                        Cf[(size_t)m * N + n] = v;
                    } else if (OUTMODE == 1) {
                        v = v / (1.0f + __expf(-v));
                        Cb[pkoff(m, n, kDFF >> 5)] = f2bf(v);   // packed for ffn2
                    } else {
                        const int rgn = n0 >> 8;               // 0=Q 1=K 2=V
                        const int nl  = n & 255;
                        const int hh  = nl >> 5, dh = nl & 31;
                        const int bb  = m >> 11, s = m & (kS - 1);
                        const int bh  = bb * kH + hh;
                        if (rgn == 0)
                            Cb[((size_t)bh * kS + s) * kDH + dh] = f2bf(v * kScaleL2E);
                        else if (rgn == 1)
                            KbP[((size_t)bh * kS + s) * kDH + dh] = f2bf(v);
                        else {
                            // quad-interleave within 32-key block
                            const int so = s & 31;
                            const int vq = (so >> 2) & 3;
                            const int vj = (so & 3) | (((so >> 4) & 1) << 2);
                            VtP[(((size_t)bh * (kS / 32) + (s >> 5)) * 4 + vq) * 256
                                + dh * 8 + vj] = f2bf(v);
                        }
                    }
                }
            }
        }
    }
}

// ---------------------------------------------------------------------------
// MFMA flash attention v15 (R2-proven math; R7-proven packed ctx store).
// Block = 4 waves: (qsub=wave>>1)*64 queries x (half=wave&1)*1024 keys,
// 128 queries/block of one (b,h). Grid (kS/128=16, 8, 4) = 512 blocks.
// ---------------------------------------------------------------------------
__global__ __launch_bounds__(256)
void attn_kernel(const u16* __restrict__ Qb, const u16* __restrict__ Kb,
                 const u16* __restrict__ Vp, u16* __restrict__ ctx)
{
    __shared__ float cbuf[2][64 * 33];     // combine buffer only (16.9 KB)
    const int tid  = threadIdx.x;
    const int wave = tid >> 6;
    const int lane = tid & 63;
    const int quad = lane >> 4;
    const int l16  = lane & 15;
    const int h = blockIdx.y;
    const int b = blockIdx.z;
    const int bh = b * kH + h;
    const int qsub = wave >> 1;
    const int half = wave & 1;
    const int q0 = blockIdx.x * 128 + qsub * 64;

    bf16x8 aq[4];
    #pragma unroll
    for (int qb = 0; qb < 4; ++qb)
        aq[qb] = *(const bf16x8*)
            &Qb[((size_t)bh * kS + q0 + qb * 16 + l16) * kDH + quad * 8];

    const u16* Kbase = Kb + (size_t)bh * kS * kDH;
    const u16* Vbase = Vp + (size_t)bh * (kS * 32);

    f32x4 O[4][2] = {};
    f32x4 lsum[4] = {};
    const f32x4 zz = {0.f, 0.f, 0.f, 0.f};
    union { u32 u[4]; bf16x8 v; } ones;
    ones.u[0] = ones.u[1] = ones.u[2] = ones.u[3] = 0x3F803F80u;

    auto load_tile = [&](int kt, bf16x8 (&kf)[4], bf16x8 (&vf)[2][2]) {
        #pragma unroll
        for (int kg = 0; kg < 4; ++kg)
            kf[kg] = *(const bf16x8*)
                &Kbase[(size_t)(kt + kg * 16 + l16) * kDH + quad * 8];
        #pragma unroll
        for (int ks = 0; ks < 2; ++ks)
            #pragma unroll
            for (int nf = 0; nf < 2; ++nf)
                vf[ks][nf] = *(const bf16x8*)
                    &Vbase[(size_t)(((kt >> 5) + ks) * 4 + quad) * 1024
                           + (nf * 16 + l16) * 8];
    };

    auto comp_tile = [&](bf16x8 (&kf)[4], bf16x8 (&vf)[2][2]) {
        #pragma unroll
        for (int qb = 0; qb < 4; ++qb) {
            f32x4 S0 = __builtin_amdgcn_mfma_f32_16x16x32_bf16(kf[0], aq[qb], zz, 0, 0, 0);
            f32x4 S1 = __builtin_amdgcn_mfma_f32_16x16x32_bf16(kf[1], aq[qb], zz, 0, 0, 0);
            f32x4 S2 = __builtin_amdgcn_mfma_f32_16x16x32_bf16(kf[2], aq[qb], zz, 0, 0, 0);
            f32x4 S3 = __builtin_amdgcn_mfma_f32_16x16x32_bf16(kf[3], aq[qb], zz, 0, 0, 0);

            union { u32 u[4]; bf16x8 v; } pA0, pA1;
            pA0.u[0] = pk_trunc(__builtin_amdgcn_exp2f(S0[0]), __builtin_amdgcn_exp2f(S0[1]));
            pA0.u[1] = pk_trunc(__builtin_amdgcn_exp2f(S0[2]), __builtin_amdgcn_exp2f(S0[3]));
            pA0.u[2] = pk_trunc(__builtin_amdgcn_exp2f(S1[0]), __builtin_amdgcn_exp2f(S1[1]));
            pA0.u[3] = pk_trunc(__builtin_amdgcn_exp2f(S1[2]), __builtin_amdgcn_exp2f(S1[3]));
            pA1.u[0] = pk_trunc(__builtin_amdgcn_exp2f(S2[0]), __builtin_amdgcn_exp2f(S2[1]));
            pA1.u[1] = pk_trunc(__builtin_amdgcn_exp2f(S2[2]), __builtin_amdgcn_exp2f(S2[3]));
            pA1.u[2] = pk_trunc(__builtin_amdgcn_exp2f(S3[0]), __builtin_amdgcn_exp2f(S3[1]));
            pA1.u[3] = pk_trunc(__builtin_amdgcn_exp2f(S3[2]), __builtin_amdgcn_exp2f(S3[3]));

            lsum[qb] = __builtin_amdgcn_mfma_f32_16x16x32_bf16(pA0.v, ones.v, lsum[qb], 0, 0, 0);
            lsum[qb] = __builtin_amdgcn_mfma_f32_16x16x32_bf16(pA1.v, ones.v, lsum[qb], 0, 0, 0);

            O[qb][0] = __builtin_amdgcn_mfma_f32_16x16x32_bf16(pA0.v, vf[0][0], O[qb][0], 0, 0, 0);
            O[qb][1] = __builtin_amdgcn_mfma_f32_16x16x32_bf16(pA0.v, vf[0][1], O[qb][1], 0, 0, 0);
            O[qb][0] = __builtin_amdgcn_mfma_f32_16x16x32_bf16(pA1.v, vf[1][0], O[qb][0], 0, 0, 0);
            O[qb][1] = __builtin_amdgcn_mfma_f32_16x16x32_bf16(pA1.v, vf[1][1], O[qb][1], 0, 0, 0);
        }
    };

    const int kbeg = half * (kS / 2);
    #pragma unroll 1
    for (int t2 = 0; t2 < 8; ++t2) {
        const int ktA = kbeg + t2 * 128;
        bf16x8 kfA[4], vfA[2][2], kfB[4], vfB[2][2];
        load_tile(ktA,      kfA, vfA);
        load_tile(ktA + 64, kfB, vfB);   // issued before tile-A compute
        comp_tile(kfA, vfA);
        comp_tile(kfB, vfB);
    }

    float* cb = cbuf[qsub];
    if (half == 1) {
        #pragma unroll
        for (int qb = 0; qb < 4; ++qb)
            #pragma unroll
            for (int r = 0; r < 4; ++r) {
                const int row = qb * 16 + quad * 4 + r;
                cb[row * 33 + l16]      = O[qb][0][r];
                cb[row * 33 + 16 + l16] = O[qb][1][r];
                if (l16 == 0)
                    cb[row * 33 + 32] = lsum[qb][r];
            }
    }
    __syncthreads();
    if (half == 0) {
        #pragma unroll
        for (int qb = 0; qb < 4; ++qb)
            #pragma unroll
            for (int r = 0; r < 4; ++r) {
                const int row = qb * 16 + quad * 4 + r;
                const float lq  = lsum[qb][r] + cb[row * 33 + 32];
                const float inv = 1.0f / lq;
                const float o0 = O[qb][0][r] + cb[row * 33 + l16];
                const float o1 = O[qb][1][r] + cb[row * 33 + 16 + l16];
                const int q = q0 + row;
                const int mrow = b * kS + q;
                // packed fragment-major ctx (cols h*32+c, c<32 -> in-tile = c)
                u16* crow = ctx + ((size_t)(mrow >> 4) * (kD >> 5) + h) * 512
                          + (mrow & 15) * 32;
                crow[l16]      = f2bf(o0 * inv);
                crow[16 + l16] = f2bf(o1 * inv);
            }
    }
}

// ---------------------------------------------------------------------------
// 7 dispatches: prep(ln1+conv_w) -> qkv -> attn -> proj(+res) -> ln2 ->
// ffn1(SiLU) -> ffn2(+res). Workspace (bytes):
//   [ 0M, 4M)  Qb   (bf16)  -- [0,8M) reused as packed h after attn
//   [ 4M, 8M)  Kb   (bf16)
//   [ 8M,12M)  Vp   (bf16, quad-interleaved)
//   [12M,16M)  ctx  (bf16, packed fragment-major)
//   [16M,20M)  y    (bf16, packed; LN1 then LN2)
//   [20M,21M)  Wb   (bf16 packed: wq|wp|w1|w2)
// ---------------------------------------------------------------------------
extern "C" void kernel_launch(void* const* d_in, const int* in_sizes, int n_in,
                              void* d_out, int out_size, void* d_ws, size_t ws_size,
                              hipStream_t stream)
{
    const float* x      = (const float*)d_in[0];
    const float* ln1_g  = (const float*)d_in[1];
    const float* ln1_b  = (const float*)d_in[2];
    const float* w_qkv  = (const float*)d_in[3];
    const float* b_qkv  = (const float*)d_in[4];
    const float* w_proj = (const float*)d_in[5];
    const float* b_proj = (const float*)d_in[6];
    const float* ln2_g  = (const float*)d_in[7];
    const float* ln2_b  = (const float*)d_in[8];
    const float* w1     = (const float*)d_in[9];
    const float* b1     = (const float*)d_in[10];
    const float* w2     = (const float*)d_in[11];
    const float* b2     = (const float*)d_in[12];
    float* out = (float*)d_out;

    char* ws = (char*)d_ws;
    u16* Qb  = (u16*)ws;
    u16* Kb  = (u16*)(ws + ((size_t)4  << 20));
    u16* Vp  = (u16*)(ws + ((size_t)8  << 20));
    u16* ctx = (u16*)(ws + ((size_t)12 << 20));
    u16* y   = (u16*)(ws + ((size_t)16 << 20));
    u16* h   = (u16*)ws;                     // aliases Qb/Kb (dead after attn)
    u16* Wb  = (u16*)(ws + ((size_t)20 << 20));
    u16* wqb = Wb;                           // 768x256 packed
    u16* wpb = Wb + 196608;                  // 256x256 packed
    u16* w1b = Wb + 262144;                  // 512x256 packed
    u16* w2b = Wb + 393216;                  // 256x512 packed

    const dim3 blk(256);

    // 1) y = packed bf16(LN1(x)); Wb = packed bf16 weights (extra 512 blocks)
    prep_kernel<<<dim3(kM / 4 + 512), blk, 0, stream>>>(
        x, ln1_g, ln1_b, y, w_qkv, w_proj, w1, w2, Wb);
    // 2) Qb/Kb/Vp = bf16(y @ w_qkv.T + b_qkv)   [NI=2, MT=2 -> grid 32x24]
    gemm_ps<2, 2, false, 256, 2><<<dim3(kMT / 2, 24), blk, 0, stream>>>(
        y, wqb, b_qkv, nullptr, nullptr, Qb, Kb, Vp, 0);
    // 3) ctx = attention (packed bf16 out)
    attn_kernel<<<dim3(kS / 128, kH, kB), blk, 0, stream>>>(Qb, Kb, Vp, ctx);
    // 4) out = x + ctx @ w_proj.T + b_proj   [NI=2, MT=2 -> grid 32x8]
    gemm_ps<2, 0, true, 256, 2><<<dim3(kMT / 2, 8), blk, 0, stream>>>(
        ctx, wpb, b_proj, x, out, nullptr, nullptr, nullptr, kD);
    // 5) y = packed bf16(LN2(out))  (no conv blocks this time)
    prep_kernel<<<dim3(kM / 4), blk, 0, stream>>>(
        out, ln2_g, ln2_b, y, nullptr, nullptr, nullptr, nullptr, nullptr);
    // 6) h = packed bf16(silu(y @ w1.T + b1))   [NI=2, MT=2 -> grid 32x16]
    gemm_ps<2, 1, false, 256, 2><<<dim3(kMT / 2, 16), blk, 0, stream>>>(
        y, w1b, b1, nullptr, nullptr, h, nullptr, nullptr, kDFF);
    // 7) out = out + h @ w2.T + b2   [K=512, NI=1, MT=2 -> grid 32x16]
    gemm_ps<1, 0, true, 512, 2><<<dim3(kMT / 2, 16), blk, 0, stream>>>(
        h, w2b, b2, out, out, nullptr, nullptr, nullptr, kD);
}

// Round 9
// 162.396 us; speedup vs baseline: 1.2754x; 1.2754x over previous
//
#include <hip/hip_runtime.h>
#include <cstddef>

// Problem constants (B=4, S=2048, D=256, H=8, dh=32, d_ff=512), fp32 in/out.
constexpr int kB   = 4;
constexpr int kS   = 2048;
constexpr int kD   = 256;
constexpr int kH   = 8;
constexpr int kDH  = 32;
constexpr int kDFF = 512;
constexpr int kM   = kB * kS;   // 8192 token rows
constexpr float kEps = 1e-5f;
// 1/sqrt(32) * log2(e): scores pre-scaled so softmax uses exp2 directly.
constexpr float kScaleL2E = 0.17677669529663687f * 1.4426950408889634f;

typedef float f32x4  __attribute__((ext_vector_type(4)));
typedef short bf16x8 __attribute__((ext_vector_type(8)));
typedef unsigned short u16;
typedef unsigned int   u32;

__device__ inline u16 f2bf(float x) {
    union { float f; unsigned u; } c; c.f = x;
    const unsigned r = c.u + 0x7fffu + ((c.u >> 16) & 1u);
    return (u16)(r >> 16);
}

// pack two fp32 -> two bf16 (truncation) in ONE v_perm_b32.
__device__ inline u32 pk_trunc(float lo, float hi) {
    union { float f; u32 u; } a, b; a.f = lo; b.f = hi;
    return __builtin_amdgcn_perm(b.u, a.u, 0x07060302u);
}

// Packed fragment-major layout (R7-proven):
//   P[row/16][col/32][row&15][col&31], 512 u16 per 16x32 tile.
// A wave-fragment load (lane quad,l16) is ONE contiguous 1KB wave-load.
__device__ inline size_t pkoff(int row, int col, int nkb) {
    return ((size_t)(row >> 4) * nkb + (col >> 5)) * 512
         + (row & 15) * 32 + (col & 31);
}

// ---------------------------------------------------------------------------
// prep_kernel = LN1 (blocks [0, kM/4)) + one-shot weight convert+pack
// (blocks [kM/4, kM/4+512)). R8-proven correct. LN: 4 rows/block, one wave
// per row, shuffle reduction, bf16 out packed. Conv: fp32 -> bf16 packed,
// same f2bf rounding. Region bases (u16): wq 0, wp 196608, w1 262144,
// w2 393216.
// ---------------------------------------------------------------------------
__global__ __launch_bounds__(256)
void prep_kernel(const float* __restrict__ x, const float* __restrict__ g,
                 const float* __restrict__ b, u16* __restrict__ y,
                 const float* __restrict__ wq, const float* __restrict__ wp,
                 const float* __restrict__ w1, const float* __restrict__ w2,
                 u16* __restrict__ wdst)
{
    if (blockIdx.x >= kM / 4) {
        const int e0 = ((blockIdx.x - kM / 4) * 256 + threadIdx.x) * 4;
        const float* src; int off, K, base;
        if (e0 < 196608)      { src = wq; off = e0;          K = 256; base = 0; }
        else if (e0 < 262144) { src = wp; off = e0 - 196608; K = 256; base = 196608; }
        else if (e0 < 393216) { src = w1; off = e0 - 262144; K = 256; base = 262144; }
        else                  { src = w2; off = e0 - 393216; K = 512; base = 393216; }
        const float4 v = *(const float4*)&src[off];
        const int n = off / K, k = off - n * K;
        const size_t po = pkoff(n, k, K >> 5);    // k%4==0 -> ushort4 in-tile
        *(ushort4*)&wdst[base + po] =
            make_ushort4(f2bf(v.x), f2bf(v.y), f2bf(v.z), f2bf(v.w));
        return;
    }
    const int wave = threadIdx.x >> 6;
    const int lane = threadIdx.x & 63;
    const int row  = blockIdx.x * 4 + wave;
    const float4 v = *(const float4*)&x[(size_t)row * kD + lane * 4];
    float s1 = (v.x + v.y) + (v.z + v.w);
    float s2 = (v.x * v.x + v.y * v.y) + (v.z * v.z + v.w * v.w);
    #pragma unroll
    for (int off = 1; off < 64; off <<= 1) {
        s1 += __shfl_xor(s1, off);
        s2 += __shfl_xor(s2, off);
    }
    const float mu  = s1 * (1.0f / kD);
    const float var = s2 * (1.0f / kD) - mu * mu;
    const float inv = rsqrtf(var + kEps);
    const float4 g4 = *(const float4*)&g[lane * 4];
    const float4 b4 = *(const float4*)&b[lane * 4];
    *(ushort4*)&y[pkoff(row, lane * 4, kD >> 5)] = make_ushort4(
        f2bf((v.x - mu) * inv * g4.x + b4.x),
        f2bf((v.y - mu) * inv * g4.y + b4.y),
        f2bf((v.z - mu) * inv * g4.z + b4.z),
        f2bf((v.w - mu) * inv * g4.w + b4.w));
}

// ---------------------------------------------------------------------------
// bf16 MFMA NT GEMM (R7-proven gemm_pk, unchanged): LDS-free, packed
// coalesced fragment loads. Block 128(M) x NI*16(N), 4 waves; wave w owns
// rows [m0+16w,+16) and [m0+64+16w,+16); each W-fragment feeds two MFMAs.
// OUTMODE: 0 = fp32 (+RES), 1 = SiLU->bf16 PACKED, 2 = QKV split.
// ---------------------------------------------------------------------------
template<int NI, int OUTMODE, bool RES, int KTOT>
__global__ __launch_bounds__(256)
void gemm_pk(const u16* __restrict__ Ap, const u16* __restrict__ Wp,
             const float* __restrict__ bias, const float* __restrict__ res,
             float* __restrict__ Cf, u16* __restrict__ Cb,
             u16* __restrict__ KbP, u16* __restrict__ VtP, int N)
{
    constexpr int NK = KTOT / 32;
    const int tid  = threadIdx.x;
    const int wave = tid >> 6;
    const int lane = tid & 63;
    const int quad = lane >> 4;
    const int l16  = lane & 15;
    const int m0 = blockIdx.x * 128;
    const int n0 = blockIdx.y * (NI * 16);
    const int fo = l16 * 32 + quad * 8;     // in-tile fragment offset

    f32x4 acc[2][NI];
    #pragma unroll
    for (int mt = 0; mt < 2; ++mt)
        #pragma unroll
        for (int ni = 0; ni < NI; ++ni) acc[mt][ni] = {0.f, 0.f, 0.f, 0.f};

    const u16* a0p = Ap + (size_t)((m0 >> 4) + wave)     * NK * 512 + fo;
    const u16* a1p = Ap + (size_t)((m0 >> 4) + 4 + wave) * NK * 512 + fo;
    const u16* wp  = Wp + (size_t)(n0 >> 4)              * NK * 512 + fo;

    #pragma unroll 2
    for (int k = 0; k < NK; ++k) {
        const bf16x8 a0 = *(const bf16x8*)&a0p[k * 512];
        const bf16x8 a1 = *(const bf16x8*)&a1p[k * 512];
        #pragma unroll
        for (int ni = 0; ni < NI; ++ni) {
            const bf16x8 wf = *(const bf16x8*)&wp[((size_t)ni * NK + k) * 512];
            acc[0][ni] = __builtin_amdgcn_mfma_f32_16x16x32_bf16(a0, wf, acc[0][ni], 0, 0, 0);
            acc[1][ni] = __builtin_amdgcn_mfma_f32_16x16x32_bf16(a1, wf, acc[1][ni], 0, 0, 0);
        }
    }

    #pragma unroll
    for (int mt = 0; mt < 2; ++mt) {
        #pragma unroll
        for (int ni = 0; ni < NI; ++ni) {
            const float bias_v = bias[n0 + ni * 16 + l16];
            #pragma unroll
            for (int r = 0; r < 4; ++r) {
                const int m = m0 + mt * 64 + wave * 16 + quad * 4 + r;
                const int n = n0 + ni * 16 + l16;
                float v = acc[mt][ni][r] + bias_v;
                if (OUTMODE == 0) {
                    if (RES) v += res[(size_t)m * N + n];
                    Cf[(size_t)m * N + n] = v;
                } else if (OUTMODE == 1) {
                    v = v / (1.0f + __expf(-v));
                    Cb[pkoff(m, n, kDFF >> 5)] = f2bf(v);   // packed for ffn2
                } else {
                    const int rgn = n0 >> 8;               // 0=Q 1=K 2=V
                    const int nl  = n & 255;
                    const int hh  = nl >> 5, dh = nl & 31;
                    const int bb  = m >> 11, s = m & (kS - 1);
                    const int bh  = bb * kH + hh;
                    if (rgn == 0)
                        Cb[((size_t)bh * kS + s) * kDH + dh] = f2bf(v * kScaleL2E);
                    else if (rgn == 1)
                        KbP[((size_t)bh * kS + s) * kDH + dh] = f2bf(v);
                    else {
                        const int so = s & 31;
                        const int vq = (so >> 2) & 3;
                        const int vj = (so & 3) | (((so >> 4) & 1) << 2);
                        VtP[(((size_t)bh * (kS / 32) + (s >> 5)) * 4 + vq) * 256
                            + dh * 8 + vj] = f2bf(v);
                    }
                }
            }
        }
    }
}

// ---------------------------------------------------------------------------
// Fused proj + residual + LN2 (NEW). One wave owns 16 rows x ALL 256 cols
// (NI=16, acc = 64 VGPR), so the LN2 row reduction is wave-local:
//   v = ctx@wp.T + b_proj + x  -> out (fp32)      [proj+residual]
//   row stats via 16-lane shfl tree (wave holds the full row)
//   y = packed bf16 LN(v)                          [replaces ln2 dispatch]
// Epilogue-side fusion only: no serial prologue chain (R3's mistake),
// no LDS, packed coalesced loads (R7-proven). 4 waves/block, 64 rows/block,
// grid = kM/64 = 128 blocks. W re-read per wave is L2-hot (128KB).
// ---------------------------------------------------------------------------
__global__ __launch_bounds__(256)
void proj_ln2_kernel(const u16* __restrict__ ctx, const u16* __restrict__ Wp,
                     const float* __restrict__ bias, const float* __restrict__ x,
                     const float* __restrict__ g, const float* __restrict__ bb,
                     float* __restrict__ out, u16* __restrict__ y)
{
    const int tid  = threadIdx.x;
    const int wave = tid >> 6;
    const int lane = tid & 63;
    const int quad = lane >> 4;
    const int l16  = lane & 15;
    const int tr   = blockIdx.x * 4 + wave;   // 16-row tile index
    const int fo   = l16 * 32 + quad * 8;

    f32x4 acc[16];
    #pragma unroll
    for (int ni = 0; ni < 16; ++ni) acc[ni] = {0.f, 0.f, 0.f, 0.f};

    const u16* ap = ctx + (size_t)tr * 8 * 512 + fo;
    #pragma unroll 2
    for (int k = 0; k < 8; ++k) {
        const bf16x8 a = *(const bf16x8*)&ap[k * 512];
        #pragma unroll
        for (int ni = 0; ni < 16; ++ni) {
            const bf16x8 wf = *(const bf16x8*)&Wp[((size_t)ni * 8 + k) * 512 + fo];
            acc[ni] = __builtin_amdgcn_mfma_f32_16x16x32_bf16(a, wf, acc[ni], 0, 0, 0);
        }
    }

    float bv[16], gv[16], bbv[16];
    #pragma unroll
    for (int ni = 0; ni < 16; ++ni) {
        bv[ni]  = bias[ni * 16 + l16];
        gv[ni]  = g[ni * 16 + l16];
        bbv[ni] = bb[ni * 16 + l16];
    }

    const int m0 = tr * 16;
    #pragma unroll
    for (int r = 0; r < 4; ++r) {
        const int m = m0 + quad * 4 + r;
        float v[16], s1 = 0.f, s2 = 0.f;
        #pragma unroll
        for (int ni = 0; ni < 16; ++ni) {
            v[ni] = acc[ni][r] + bv[ni] + x[(size_t)m * kD + ni * 16 + l16];
            out[(size_t)m * kD + ni * 16 + l16] = v[ni];
            s1 += v[ni];
            s2 += v[ni] * v[ni];
        }
        // full-row reduction within the 16-lane group (masks < 16)
        s1 += __shfl_xor(s1, 1); s2 += __shfl_xor(s2, 1);
        s1 += __shfl_xor(s1, 2); s2 += __shfl_xor(s2, 2);
        s1 += __shfl_xor(s1, 4); s2 += __shfl_xor(s2, 4);
        s1 += __shfl_xor(s1, 8); s2 += __shfl_xor(s2, 8);
        const float mu  = s1 * (1.0f / kD);
        const float var = s2 * (1.0f / kD) - mu * mu;
        const float inv = rsqrtf(var + kEps);
        // packed y write: tile row = tr, in-tile row = quad*4+r
        u16* yb = y + (size_t)tr * 8 * 512 + (quad * 4 + r) * 32 + l16;
        #pragma unroll
        for (int ni = 0; ni < 16; ++ni)
            yb[(ni >> 1) * 512 + (ni & 1) * 16] =
                f2bf((v[ni] - mu) * inv * gv[ni] + bbv[ni]);
    }
}

// ---------------------------------------------------------------------------
// MFMA flash attention v15 (R2-proven math; R7-proven packed ctx store).
// Block = 4 waves: (qsub=wave>>1)*64 queries x (half=wave&1)*1024 keys.
// Grid (kS/128=16, 8, 4) = 512 blocks.
// ---------------------------------------------------------------------------
__global__ __launch_bounds__(256)
void attn_kernel(const u16* __restrict__ Qb, const u16* __restrict__ Kb,
                 const u16* __restrict__ Vp, u16* __restrict__ ctx)
{
    __shared__ float cbuf[2][64 * 33];     // combine buffer only (16.9 KB)
    const int tid  = threadIdx.x;
    const int wave = tid >> 6;
    const int lane = tid & 63;
    const int quad = lane >> 4;
    const int l16  = lane & 15;
    const int h = blockIdx.y;
    const int b = blockIdx.z;
    const int bh = b * kH + h;
    const int qsub = wave >> 1;
    const int half = wave & 1;
    const int q0 = blockIdx.x * 128 + qsub * 64;

    bf16x8 aq[4];
    #pragma unroll
    for (int qb = 0; qb < 4; ++qb)
        aq[qb] = *(const bf16x8*)
            &Qb[((size_t)bh * kS + q0 + qb * 16 + l16) * kDH + quad * 8];

    const u16* Kbase = Kb + (size_t)bh * kS * kDH;
    const u16* Vbase = Vp + (size_t)bh * (kS * 32);

    f32x4 O[4][2] = {};
    f32x4 lsum[4] = {};
    const f32x4 zz = {0.f, 0.f, 0.f, 0.f};
    union { u32 u[4]; bf16x8 v; } ones;
    ones.u[0] = ones.u[1] = ones.u[2] = ones.u[3] = 0x3F803F80u;

    auto load_tile = [&](int kt, bf16x8 (&kf)[4], bf16x8 (&vf)[2][2]) {
        #pragma unroll
        for (int kg = 0; kg < 4; ++kg)
            kf[kg] = *(const bf16x8*)
                &Kbase[(size_t)(kt + kg * 16 + l16) * kDH + quad * 8];
        #pragma unroll
        for (int ks = 0; ks < 2; ++ks)
            #pragma unroll
            for (int nf = 0; nf < 2; ++nf)
                vf[ks][nf] = *(const bf16x8*)
                    &Vbase[(size_t)(((kt >> 5) + ks) * 4 + quad) * 1024
                           + (nf * 16 + l16) * 8];
    };

    auto comp_tile = [&](bf16x8 (&kf)[4], bf16x8 (&vf)[2][2]) {
        #pragma unroll
        for (int qb = 0; qb < 4; ++qb) {
            f32x4 S0 = __builtin_amdgcn_mfma_f32_16x16x32_bf16(kf[0], aq[qb], zz, 0, 0, 0);
            f32x4 S1 = __builtin_amdgcn_mfma_f32_16x16x32_bf16(kf[1], aq[qb], zz, 0, 0, 0);
            f32x4 S2 = __builtin_amdgcn_mfma_f32_16x16x32_bf16(kf[2], aq[qb], zz, 0, 0, 0);
            f32x4 S3 = __builtin_amdgcn_mfma_f32_16x16x32_bf16(kf[3], aq[qb], zz, 0, 0, 0);

            union { u32 u[4]; bf16x8 v; } pA0, pA1;
            pA0.u[0] = pk_trunc(__builtin_amdgcn_exp2f(S0[0]), __builtin_amdgcn_exp2f(S0[1]));
            pA0.u[1] = pk_trunc(__builtin_amdgcn_exp2f(S0[2]), __builtin_amdgcn_exp2f(S0[3]));
            pA0.u[2] = pk_trunc(__builtin_amdgcn_exp2f(S1[0]), __builtin_amdgcn_exp2f(S1[1]));
            pA0.u[3] = pk_trunc(__builtin_amdgcn_exp2f(S1[2]), __builtin_amdgcn_exp2f(S1[3]));
            pA1.u[0] = pk_trunc(__builtin_amdgcn_exp2f(S2[0]), __builtin_amdgcn_exp2f(S2[1]));
            pA1.u[1] = pk_trunc(__builtin_amdgcn_exp2f(S2[2]), __builtin_amdgcn_exp2f(S2[3]));
            pA1.u[2] = pk_trunc(__builtin_amdgcn_exp2f(S3[0]), __builtin_amdgcn_exp2f(S3[1]));
            pA1.u[3] = pk_trunc(__builtin_amdgcn_exp2f(S3[2]), __builtin_amdgcn_exp2f(S3[3]));

            lsum[qb] = __builtin_amdgcn_mfma_f32_16x16x32_bf16(pA0.v, ones.v, lsum[qb], 0, 0, 0);
            lsum[qb] = __builtin_amdgcn_mfma_f32_16x16x32_bf16(pA1.v, ones.v, lsum[qb], 0, 0, 0);

            O[qb][0] = __builtin_amdgcn_mfma_f32_16x16x32_bf16(pA0.v, vf[0][0], O[qb][0], 0, 0, 0);
            O[qb][1] = __builtin_amdgcn_mfma_f32_16x16x32_bf16(pA0.v, vf[0][1], O[qb][1], 0, 0, 0);
            O[qb][0] = __builtin_amdgcn_mfma_f32_16x16x32_bf16(pA1.v, vf[1][0], O[qb][0], 0, 0, 0);
            O[qb][1] = __builtin_amdgcn_mfma_f32_16x16x32_bf16(pA1.v, vf[1][1], O[qb][1], 0, 0, 0);
        }
    };

    const int kbeg = half * (kS / 2);
    #pragma unroll 1
    for (int t2 = 0; t2 < 8; ++t2) {
        const int ktA = kbeg + t2 * 128;
        bf16x8 kfA[4], vfA[2][2], kfB[4], vfB[2][2];
        load_tile(ktA,      kfA, vfA);
        load_tile(ktA + 64, kfB, vfB);   // issued before tile-A compute
        comp_tile(kfA, vfA);
        comp_tile(kfB, vfB);
    }

    float* cb = cbuf[qsub];
    if (half == 1) {
        #pragma unroll
        for (int qb = 0; qb < 4; ++qb)
            #pragma unroll
            for (int r = 0; r < 4; ++r) {
                const int row = qb * 16 + quad * 4 + r;
                cb[row * 33 + l16]      = O[qb][0][r];
                cb[row * 33 + 16 + l16] = O[qb][1][r];
                if (l16 == 0)
                    cb[row * 33 + 32] = lsum[qb][r];
            }
    }
    __syncthreads();
    if (half == 0) {
        #pragma unroll
        for (int qb = 0; qb < 4; ++qb)
            #pragma unroll
            for (int r = 0; r < 4; ++r) {
                const int row = qb * 16 + quad * 4 + r;
                const float lq  = lsum[qb][r] + cb[row * 33 + 32];
                const float inv = 1.0f / lq;
                const float o0 = O[qb][0][r] + cb[row * 33 + l16];
                const float o1 = O[qb][1][r] + cb[row * 33 + 16 + l16];
                const int q = q0 + row;
                const int mrow = b * kS + q;
                // packed fragment-major ctx (cols h*32+c, c<32 -> in-tile = c)
                u16* crow = ctx + ((size_t)(mrow >> 4) * (kD >> 5) + h) * 512
                          + (mrow & 15) * 32;
                crow[l16]      = f2bf(o0 * inv);
                crow[16 + l16] = f2bf(o1 * inv);
            }
    }
}

// ---------------------------------------------------------------------------
// 6 dispatches: prep(ln1+conv_w) -> qkv -> attn -> proj+res+ln2(fused) ->
// ffn1(SiLU) -> ffn2(+res). Workspace (bytes):
//   [ 0M, 4M)  Qb   (bf16)  -- [0,8M) reused as packed h after attn
//   [ 4M, 8M)  Kb   (bf16)
//   [ 8M,12M)  Vp   (bf16, quad-interleaved)
//   [12M,16M)  ctx  (bf16, packed fragment-major)
//   [16M,20M)  y    (bf16, packed; LN1 then LN2)
//   [20M,21M)  Wb   (bf16 packed: wq|wp|w1|w2)
// ---------------------------------------------------------------------------
extern "C" void kernel_launch(void* const* d_in, const int* in_sizes, int n_in,
                              void* d_out, int out_size, void* d_ws, size_t ws_size,
                              hipStream_t stream)
{
    const float* x      = (const float*)d_in[0];
    const float* ln1_g  = (const float*)d_in[1];
    const float* ln1_b  = (const float*)d_in[2];
    const float* w_qkv  = (const float*)d_in[3];
    const float* b_qkv  = (const float*)d_in[4];
    const float* w_proj = (const float*)d_in[5];
    const float* b_proj = (const float*)d_in[6];
    const float* ln2_g  = (const float*)d_in[7];
    const float* ln2_b  = (const float*)d_in[8];
    const float* w1     = (const float*)d_in[9];
    const float* b1     = (const float*)d_in[10];
    const float* w2     = (const float*)d_in[11];
    const float* b2     = (const float*)d_in[12];
    float* out = (float*)d_out;

    char* ws = (char*)d_ws;
    u16* Qb  = (u16*)ws;
    u16* Kb  = (u16*)(ws + ((size_t)4  << 20));
    u16* Vp  = (u16*)(ws + ((size_t)8  << 20));
    u16* ctx = (u16*)(ws + ((size_t)12 << 20));
    u16* y   = (u16*)(ws + ((size_t)16 << 20));
    u16* h   = (u16*)ws;                     // aliases Qb/Kb (dead after attn)
    u16* Wb  = (u16*)(ws + ((size_t)20 << 20));
    u16* wqb = Wb;                           // 768x256 packed
    u16* wpb = Wb + 196608;                  // 256x256 packed
    u16* w1b = Wb + 262144;                  // 512x256 packed
    u16* w2b = Wb + 393216;                  // 256x512 packed

    const dim3 blk(256);

    // 1) y = packed bf16(LN1(x)); Wb = packed bf16 weights (extra 512 blocks)
    prep_kernel<<<dim3(kM / 4 + 512), blk, 0, stream>>>(
        x, ln1_g, ln1_b, y, w_qkv, w_proj, w1, w2, Wb);
    // 2) Qb/Kb/Vp = bf16(y @ w_qkv.T + b_qkv)
    gemm_pk<4, 2, false, 256><<<dim3(kM / 128, 12), blk, 0, stream>>>(
        y, wqb, b_qkv, nullptr, nullptr, Qb, Kb, Vp, 0);
    // 3) ctx = attention (packed bf16 out)
    attn_kernel<<<dim3(kS / 128, kH, kB), blk, 0, stream>>>(Qb, Kb, Vp, ctx);
    // 4) out = x + ctx @ w_proj.T + b_proj; y = packed bf16(LN2(out))  [fused]
    proj_ln2_kernel<<<dim3(kM / 64), blk, 0, stream>>>(
        ctx, wpb, b_proj, x, ln2_g, ln2_b, out, y);
    // 5) h = packed bf16(silu(y @ w1.T + b1))
    gemm_pk<4, 1, false, 256><<<dim3(kM / 128, kDFF / 64), blk, 0, stream>>>(
        y, w1b, b1, nullptr, nullptr, h, nullptr, nullptr, kDFF);
    // 6) out = out + h @ w2.T + b2   (fp32, K=512; N = output stride = kD)
    gemm_pk<2, 0, true, 512><<<dim3(kM / 128, kD / 32), blk, 0, stream>>>(
        h, w2b, b2, out, out, nullptr, nullptr, nullptr, kD);
}